// Round 1
// baseline (2272.460 us; speedup 1.0000x reference)
//
#include <hip/hip_runtime.h>
#include <math.h>

// Problem constants (ModConv2d_7791070675251)
#define BB   8
#define CIN  512
#define COUT 512
#define SCH  512
#define HH   64
#define WW   64

// affine scale = 1/sqrt(512), conv scale = 1/sqrt(512*9)
#define AFF_SCALE 0.044194173824159216f
#define CONV_SCALE 0.014731391274719736f
#define CONV_SCALE2 (1.0f/4608.0f)

// ---------------------------------------------------------------------------
// Kernel 1: smod[b*CIN+ic] = dot(style[b,:], w_affine[ic,:]) * AFF_SCALE + ba[ic]
// One wave per dot product. Grid = BB*CIN/4 blocks of 256 threads.
// ---------------------------------------------------------------------------
__global__ __launch_bounds__(256) void affine_kernel(
    const float* __restrict__ style, const float* __restrict__ wa,
    const float* __restrict__ ba, float* __restrict__ smod) {
  int wid  = (blockIdx.x << 2) + (threadIdx.x >> 6);   // global wave id = b*CIN+ic
  int lane = threadIdx.x & 63;
  int b  = wid >> 9;
  int ic = wid & 511;
  const float* s = style + b * SCH;
  const float* w = wa + (size_t)ic * SCH;
  float sum = 0.f;
#pragma unroll
  for (int k = 0; k < SCH / 64; ++k) sum += s[lane + 64 * k] * w[lane + 64 * k];
#pragma unroll
  for (int off = 32; off; off >>= 1) sum += __shfl_down(sum, off, 64);
  if (lane == 0) smod[wid] = sum * AFF_SCALE + ba[ic];
}

// ---------------------------------------------------------------------------
// Kernel 2: wsq[oc*CIN+ic] = sum_k w_conv[oc,ic,k]^2  (k over 3x3)
// ---------------------------------------------------------------------------
__global__ __launch_bounds__(256) void wsq_kernel(
    const float* __restrict__ wc, float* __restrict__ wsq) {
  int i = blockIdx.x * 256 + threadIdx.x;   // i = oc*CIN + ic, < COUT*CIN
  const float* p = wc + (size_t)i * 9;
  float s = 0.f;
#pragma unroll
  for (int k = 0; k < 9; ++k) { float v = p[k]; s += v * v; }
  wsq[i] = s;
}

// ---------------------------------------------------------------------------
// Kernel 3: demod[b*COUT+oc] = rsqrt(CS2 * sum_ic smod^2 * wsq + eps) * CS
// One wave per (b, oc).
// ---------------------------------------------------------------------------
__global__ __launch_bounds__(256) void demod_kernel(
    const float* __restrict__ smod, const float* __restrict__ wsq,
    float* __restrict__ demod) {
  int wid  = (blockIdx.x << 2) + (threadIdx.x >> 6);
  int lane = threadIdx.x & 63;
  int b  = wid >> 9;
  int oc = wid & 511;
  const float* s = smod + b * CIN;
  const float* w = wsq + (size_t)oc * CIN;
  float sum = 0.f;
#pragma unroll
  for (int k = 0; k < CIN / 64; ++k) {
    float sv = s[lane + 64 * k];
    sum += sv * sv * w[lane + 64 * k];
  }
#pragma unroll
  for (int off = 32; off; off >>= 1) sum += __shfl_down(sum, off, 64);
  if (lane == 0) demod[wid] = rsqrtf(sum * CONV_SCALE2 + 1e-8f) * CONV_SCALE;
}

// ---------------------------------------------------------------------------
// Kernel 4: shared-weight 3x3 conv on modulated input, demod on epilogue.
// Block: 256 threads -> 16 oc x (32x32) pixel tile for one batch b.
// Grid: 8 b * 32 ocb * 4 tiles = 1024 blocks (= 4 blocks/CU exactly).
// LDS: 34x34 input halo tile, row stride 36 (conflict-free: 2 lanes/bank).
// Weights read with wave-uniform addresses (compiler scalarizes to s_load).
// ---------------------------------------------------------------------------
__global__ __launch_bounds__(256) void conv_kernel(
    const float* __restrict__ x, const float* __restrict__ wc,
    const float* __restrict__ smod, const float* __restrict__ demod,
    float* __restrict__ out) {
  __shared__ float xs[34][36];

  int tid  = threadIdx.x;
  int blk  = blockIdx.x;
  int tile = blk & 3;
  int ocb  = (blk >> 2) & 31;
  int b    = blk >> 7;
  int oc0  = ocb << 4;
  int ty0  = (tile >> 1) << 5;
  int tx0  = (tile & 1) << 5;
  int col  = tid & 31;      // x within tile
  int row0 = tid >> 5;      // base y within tile (0..7); pixels at row0+8p

  float acc[16][4];
#pragma unroll
  for (int i = 0; i < 16; ++i)
#pragma unroll
    for (int p = 0; p < 4; ++p) acc[i][p] = 0.f;

  const float* xb = x + (size_t)b * CIN * HH * WW;

  for (int ic = 0; ic < CIN; ++ic) {
    float sv = smod[b * CIN + ic];
    const float* xc = xb + (size_t)ic * HH * WW;

    __syncthreads();   // protect xs from previous iteration's readers
    for (int idx = tid; idx < 34 * 34; idx += 256) {
      int r = idx / 34;
      int c = idx - r * 34;
      int gy = ty0 - 1 + r;
      int gx = tx0 - 1 + c;
      float v = 0.f;
      if (gy >= 0 && gy < HH && gx >= 0 && gx < WW) v = xc[gy * WW + gx];
      xs[r][c] = v * sv;
    }
    __syncthreads();

    const float* wb = wc + ((size_t)oc0 * CIN + ic) * 9;
#pragma unroll
    for (int kh = 0; kh < 3; ++kh) {
#pragma unroll
      for (int kw = 0; kw < 3; ++kw) {
        float x0 = xs[row0 + kh][col + kw];
        float x1 = xs[row0 + 8 + kh][col + kw];
        float x2 = xs[row0 + 16 + kh][col + kw];
        float x3 = xs[row0 + 24 + kh][col + kw];
#pragma unroll
        for (int oc = 0; oc < 16; ++oc) {
          float wv = wb[(size_t)oc * CIN * 9 + kh * 3 + kw];  // wave-uniform
          acc[oc][0] += wv * x0;
          acc[oc][1] += wv * x1;
          acc[oc][2] += wv * x2;
          acc[oc][3] += wv * x3;
        }
      }
    }
  }

#pragma unroll
  for (int oc = 0; oc < 16; ++oc) {
    float d = demod[b * COUT + oc0 + oc];
#pragma unroll
    for (int p = 0; p < 4; ++p) {
      int y = ty0 + row0 + 8 * p;
      out[(((size_t)b * COUT + oc0 + oc) * HH + y) * WW + tx0 + col] =
          acc[oc][p] * d;
    }
  }
}

// ---------------------------------------------------------------------------
extern "C" void kernel_launch(void* const* d_in, const int* in_sizes, int n_in,
                              void* d_out, int out_size, void* d_ws, size_t ws_size,
                              hipStream_t stream) {
  const float* input  = (const float*)d_in[0];  // [8,512,64,64]
  const float* style  = (const float*)d_in[1];  // [8,512]
  const float* wa     = (const float*)d_in[2];  // [512,512]
  const float* ba     = (const float*)d_in[3];  // [1,512]
  const float* wconv  = (const float*)d_in[4];  // [512,512,3,3]
  float* out = (float*)d_out;

  float* smod  = (float*)d_ws;                  // BB*CIN    = 4096 f
  float* demod = smod + BB * CIN;               // BB*COUT   = 4096 f
  float* wsq   = demod + BB * COUT;             // COUT*CIN  = 262144 f  (~1.06 MB total)

  affine_kernel<<<BB * CIN / 4, 256, 0, stream>>>(style, wa, ba, smod);
  wsq_kernel<<<COUT * CIN / 256, 256, 0, stream>>>(wconv, wsq);
  demod_kernel<<<BB * COUT / 4, 256, 0, stream>>>(smod, wsq, demod);
  conv_kernel<<<BB * (COUT / 16) * 4, 256, 0, stream>>>(input, wconv, smod, demod, out);
}

// Round 2
// 163.872 us; speedup vs baseline: 13.8673x; 13.8673x over previous
//
#include <hip/hip_runtime.h>
#include <hip/hip_bf16.h>

#define BB 8
#define CIN 512
#define COUT 512
#define HH 64
#define WW 64

#define AFF_SCALE 0.044194173824159216f     // 1/sqrt(512)
#define CONV_SCALE 0.014731391274719736f    // 1/sqrt(4608)
#define CONV_SCALE2 (1.0f/4608.0f)

typedef short s16x8 __attribute__((ext_vector_type(8)));
typedef float f32x4 __attribute__((ext_vector_type(4)));

__device__ __forceinline__ unsigned short f2bf(float f) {
  __hip_bfloat16 h = __float2bfloat16(f);
  return *reinterpret_cast<unsigned short*>(&h);
}

// ---------------------------------------------------------------------------
// smod[b*CIN+ic] = dot(style[b,:], w_affine[ic,:]) * AFF_SCALE + ba[ic]
// ---------------------------------------------------------------------------
__global__ __launch_bounds__(256) void affine_kernel(
    const float* __restrict__ style, const float* __restrict__ wa,
    const float* __restrict__ ba, float* __restrict__ smod) {
  int wid  = (blockIdx.x << 2) + (threadIdx.x >> 6);
  int lane = threadIdx.x & 63;
  int b  = wid >> 9;
  int ic = wid & 511;
  const float* s = style + b * CIN;
  const float* w = wa + (size_t)ic * CIN;
  float sum = 0.f;
#pragma unroll
  for (int k = 0; k < CIN / 64; ++k) sum += s[lane + 64 * k] * w[lane + 64 * k];
#pragma unroll
  for (int off = 32; off; off >>= 1) sum += __shfl_down(sum, off, 64);
  if (lane == 0) smod[wid] = sum * AFF_SCALE + ba[ic];
}

// ---------------------------------------------------------------------------
// wsq[oc*CIN+ic] = sum_k w_conv[oc,ic,k]^2
// ---------------------------------------------------------------------------
__global__ __launch_bounds__(256) void wsq_kernel(
    const float* __restrict__ wc, float* __restrict__ wsq) {
  int i = blockIdx.x * 256 + threadIdx.x;
  const float* p = wc + (size_t)i * 9;
  float s = 0.f;
#pragma unroll
  for (int k = 0; k < 9; ++k) { float v = p[k]; s += v * v; }
  wsq[i] = s;
}

// ---------------------------------------------------------------------------
// demod[b*COUT+oc] = rsqrt(CS2 * sum_ic smod^2 * wsq + eps) * CS
// ---------------------------------------------------------------------------
__global__ __launch_bounds__(256) void demod_kernel(
    const float* __restrict__ smod, const float* __restrict__ wsq,
    float* __restrict__ demod) {
  int wid  = (blockIdx.x << 2) + (threadIdx.x >> 6);
  int lane = threadIdx.x & 63;
  int b  = wid >> 9;
  int oc = wid & 511;
  const float* s = smod + b * CIN;
  const float* w = wsq + (size_t)oc * CIN;
  float sum = 0.f;
#pragma unroll
  for (int k = 0; k < CIN / 64; ++k) {
    float sv = s[lane + 64 * k];
    sum += sv * sv * w[lane + 64 * k];
  }
#pragma unroll
  for (int off = 32; off; off >>= 1) sum += __shfl_down(sum, off, 64);
  if (lane == 0) demod[wid] = rsqrtf(sum * CONV_SCALE2 + 1e-8f) * CONV_SCALE;
}

// ---------------------------------------------------------------------------
// premod: xt[b][g][y][x][ic32] bf16 = input[b][ic][y][x] * smod[b][ic]
// n-th thread writes the n-th 16B chunk (fully coalesced writes).
// ---------------------------------------------------------------------------
__global__ __launch_bounds__(256) void premod_kernel(
    const float* __restrict__ xin, const float* __restrict__ smod,
    ushort* __restrict__ xt) {
  int n = blockIdx.x * 256 + threadIdx.x;   // < 2,097,152
  int kg = n & 3;
  int x  = (n >> 2) & 63;
  int y  = (n >> 8) & 63;
  int g  = (n >> 14) & 15;
  int b  = n >> 18;
  int ic0 = g * 32 + kg * 8;
  const float* sp = smod + b * CIN + ic0;
  const float* xp = xin + (((size_t)b * CIN + ic0) * HH + y) * WW + x;
  s16x8 o;
#pragma unroll
  for (int j = 0; j < 8; ++j) {
    float v = xp[(size_t)j * HH * WW] * sp[j];
    o[j] = (short)f2bf(v);
  }
  *(s16x8*)(xt + (size_t)n * 8) = o;
}

// ---------------------------------------------------------------------------
// wpack: wfrag[g][tap][ocg][lane][8] bf16, exact A-fragment lane order:
//   element = wc[oc = ocg*16 + (l&15)][ic = g*32 + (l>>4)*8 + j][kh][kw]
// ---------------------------------------------------------------------------
__global__ __launch_bounds__(256) void wpack_kernel(
    const float* __restrict__ wc, ushort* __restrict__ wfrag) {
  int n = blockIdx.x * 256 + threadIdx.x;   // < 294,912
  int l = n & 63;
  int rem = n >> 6;
  int ocg = rem & 31;
  int rem2 = rem >> 5;          // < 144
  int tap = rem2 % 9;
  int g   = rem2 / 9;
  int oc  = ocg * 16 + (l & 15);
  int ic0 = g * 32 + (l >> 4) * 8;
  int kh = tap / 3, kw = tap - kh * 3;
  s16x8 o;
#pragma unroll
  for (int j = 0; j < 8; ++j) {
    float v = wc[((size_t)oc * CIN + ic0 + j) * 9 + kh * 3 + kw];
    o[j] = (short)f2bf(v);
  }
  *(s16x8*)(wfrag + (size_t)n * 8) = o;
}

// ---------------------------------------------------------------------------
// conv_mfma: implicit-GEMM 3x3 conv, bf16 MFMA 16x16x32, f32 accum.
// Block: 256 thr (4 waves). Block tile: 128 oc x (4 rows x 64 px).
// Wave tile: 128 oc x 64 px = 8(m) x 4(n) fragments, 128 acc VGPRs.
// K-loop: g = ic-block of 32 (16 iters) x 9 taps, ws double-buffered.
// xs layout: [row6][colhi9][kg4][col&7][16B]  (2-cover bank mapping)
// ---------------------------------------------------------------------------
#define XS_ROWSZ 4608
#define XS_SIZE  (6 * XS_ROWSZ)    // 27648 B
#define WS_SIZE  8192

__global__ __launch_bounds__(256, 2) void conv_mfma(
    const ushort* __restrict__ xt,     // [8][16][64][64][32] bf16
    const ushort* __restrict__ wfrag,  // [16][9][32][64][8] bf16
    const float* __restrict__ demod,
    float* __restrict__ out) {
  __shared__ char lds[XS_SIZE + 2 * WS_SIZE];
  char* xs  = lds;
  char* ws0 = lds + XS_SIZE;

  int tid = threadIdx.x;
  int l = tid & 63, w = tid >> 6;
  int bid = blockIdx.x;
  int ocb = bid & 3;            // 4 oc-blocks of 128; pins ocb to XCD pairs
  int b   = (bid >> 2) & 7;
  int yt  = bid >> 5;           // 0..15
  int y0  = yt * 4;

  f32x4 acc[8][4];
#pragma unroll
  for (int i = 0; i < 8; ++i)
#pragma unroll
    for (int j = 0; j < 4; ++j) acc[i][j] = f32x4{0.f, 0.f, 0.f, 0.f};

  // zero halo columns (ct = 0 and ct = 65), written once
  if (tid < 48) {
    int r = tid >> 3, kgh = (tid >> 1) & 3, side = tid & 1;
    int ct = side ? 65 : 0;
    int off = r * XS_ROWSZ + (ct >> 3) * 512 + kgh * 128 + (ct & 7) * 16;
    *(int4*)(xs + off) = int4{0, 0, 0, 0};
  }
  __syncthreads();

  // staging constants: thread -> (x = tid&63, kg = wave)
  int sx = tid & 63;
  int skg = w;
  int sct = sx + 1;
  int xs_woff = (sct >> 3) * 512 + skg * 128 + (sct & 7) * 16;

  for (int g = 0; g < 16; ++g) {
    // ---- stage xs (6 rows) + ws buffer 0 (tap 0) ----
    int4 xv[6];
#pragma unroll
    for (int r = 0; r < 6; ++r) {
      int gy = y0 - 1 + r;
      int4 t = {0, 0, 0, 0};
      if (gy >= 0 && gy < HH)
        t = *(const int4*)(xt + ((((size_t)(b * 16 + g) * 4096) + gy * 64 + sx) * 32 + skg * 8));
      xv[r] = t;
    }
    int4 wv0, wv1;
    {
      const int4* wsrc = (const int4*)(wfrag + ((size_t)(g * 9 + 0) * 32 + ocb * 8) * 512);
      wv0 = wsrc[tid];
      wv1 = wsrc[tid + 256];
    }
#pragma unroll
    for (int r = 0; r < 6; ++r) *(int4*)(xs + r * XS_ROWSZ + xs_woff) = xv[r];
    *(int4*)(ws0 + tid * 16) = wv0;
    *(int4*)(ws0 + tid * 16 + 4096) = wv1;
    __syncthreads();

#pragma unroll
    for (int tap = 0; tap < 9; ++tap) {
      char* wscur = ws0 + (tap & 1) * WS_SIZE;
      // issue next tap's weight loads early (latency hides under MFMAs)
      int4 nv0, nv1;
      if (tap < 8) {
        const int4* wsrc = (const int4*)(wfrag + ((size_t)(g * 9 + tap + 1) * 32 + ocb * 8) * 512);
        nv0 = wsrc[tid];
        nv1 = wsrc[tid + 256];
      }
      const int dy = tap / 3 - 1, dx = tap % 3 - 1;
      const int rb = w + 1 + dy;           // xs row for this wave+tap
      s16x8 bfr[4];
#pragma unroll
      for (int fn = 0; fn < 4; ++fn) {
        int c2 = fn * 16 + (l & 15) + dx + 1;   // 0..65
        bfr[fn] = *(const s16x8*)(xs + rb * XS_ROWSZ + (c2 >> 3) * 512 + (l >> 4) * 128 + (c2 & 7) * 16);
      }
#pragma unroll
      for (int fm = 0; fm < 8; ++fm) {
        s16x8 afr = *(const s16x8*)(wscur + fm * 1024 + l * 16);
#pragma unroll
        for (int fn = 0; fn < 4; ++fn)
          acc[fm][fn] = __builtin_amdgcn_mfma_f32_16x16x32_bf16(afr, bfr[fn], acc[fm][fn], 0, 0, 0);
      }
      if (tap < 8) {
        char* wsnxt = ws0 + ((tap + 1) & 1) * WS_SIZE;
        *(int4*)(wsnxt + tid * 16) = nv0;
        *(int4*)(wsnxt + tid * 16 + 4096) = nv1;
      }
      __syncthreads();
    }
  }

  // ---- epilogue: demod scale + store ----
  int oc_base = ocb * 128;
  int gy = y0 + w;
#pragma unroll
  for (int fm = 0; fm < 8; ++fm) {
#pragma unroll
    for (int r = 0; r < 4; ++r) {
      int oc = oc_base + fm * 16 + (l >> 4) * 4 + r;
      float dm = demod[b * COUT + oc];
#pragma unroll
      for (int fn = 0; fn < 4; ++fn) {
        out[(((size_t)b * COUT + oc) * 4096) + gy * 64 + fn * 16 + (l & 15)] =
            acc[fm][fn][r] * dm;
      }
    }
  }
}

// ---------------------------------------------------------------------------
extern "C" void kernel_launch(void* const* d_in, const int* in_sizes, int n_in,
                              void* d_out, int out_size, void* d_ws, size_t ws_size,
                              hipStream_t stream) {
  const float* input = (const float*)d_in[0];  // [8,512,64,64]
  const float* style = (const float*)d_in[1];  // [8,512]
  const float* wa    = (const float*)d_in[2];  // [512,512]
  const float* ba    = (const float*)d_in[3];  // [1,512]
  const float* wconv = (const float*)d_in[4];  // [512,512,3,3]
  float* out = (float*)d_out;

  float* smod  = (float*)d_ws;                    // 4096 f
  float* demod = smod + BB * CIN;                 // 4096 f
  float* wsq   = demod + BB * COUT;               // 262144 f
  ushort* wfrag = (ushort*)(wsq + (size_t)COUT * CIN);   // 2,359,296 us (4.5 MB)
  ushort* xt    = wfrag + (size_t)16 * 9 * 32 * 64 * 8;  // 16,777,216 us (32 MB)

  affine_kernel<<<BB * CIN / 4, 256, 0, stream>>>(style, wa, ba, smod);
  wsq_kernel<<<COUT * CIN / 256, 256, 0, stream>>>(wconv, wsq);
  demod_kernel<<<BB * COUT / 4, 256, 0, stream>>>(smod, wsq, demod);
  wpack_kernel<<<16 * 9 * 32 * 64 / 256, 256, 0, stream>>>(wconv, wfrag);
  premod_kernel<<<BB * 16 * 64 * 64 * 4 / 256, 256, 0, stream>>>(input, smod, xt);
  conv_mfma<<<BB * 4 * 16, 256, 0, stream>>>(xt, wfrag, demod, out);
}

// Round 3
// 156.587 us; speedup vs baseline: 14.5125x; 1.0465x over previous
//
#include <hip/hip_runtime.h>
#include <hip/hip_bf16.h>

#define BB 8
#define CIN 512
#define COUT 512
#define HH 64
#define WW 64

#define AFF_SCALE 0.044194173824159216f     // 1/sqrt(512)
#define CONV_SCALE 0.014731391274719736f    // 1/sqrt(4608)
#define CONV_SCALE2 (1.0f/4608.0f)

typedef short s16x8 __attribute__((ext_vector_type(8)));
typedef float f32x4 __attribute__((ext_vector_type(4)));

__device__ __forceinline__ unsigned short f2bf(float f) {
  __hip_bfloat16 h = __float2bfloat16(f);
  return *reinterpret_cast<unsigned short*>(&h);
}

// ---------------------------------------------------------------------------
// smod[b*CIN+ic] = dot(style[b,:], w_affine[ic,:]) * AFF_SCALE + ba[ic]
// ---------------------------------------------------------------------------
__global__ __launch_bounds__(256) void affine_kernel(
    const float* __restrict__ style, const float* __restrict__ wa,
    const float* __restrict__ ba, float* __restrict__ smod) {
  int wid  = (blockIdx.x << 2) + (threadIdx.x >> 6);
  int lane = threadIdx.x & 63;
  int b  = wid >> 9;
  int ic = wid & 511;
  const float* s = style + b * CIN;
  const float* w = wa + (size_t)ic * CIN;
  float sum = 0.f;
#pragma unroll
  for (int k = 0; k < CIN / 64; ++k) sum += s[lane + 64 * k] * w[lane + 64 * k];
#pragma unroll
  for (int off = 32; off; off >>= 1) sum += __shfl_down(sum, off, 64);
  if (lane == 0) smod[wid] = sum * AFF_SCALE + ba[ic];
}

// ---------------------------------------------------------------------------
// wsq[oc*CIN+ic] = sum_k w_conv[oc,ic,k]^2
// ---------------------------------------------------------------------------
__global__ __launch_bounds__(256) void wsq_kernel(
    const float* __restrict__ wc, float* __restrict__ wsq) {
  int i = blockIdx.x * 256 + threadIdx.x;
  const float* p = wc + (size_t)i * 9;
  float s = 0.f;
#pragma unroll
  for (int k = 0; k < 9; ++k) { float v = p[k]; s += v * v; }
  wsq[i] = s;
}

// ---------------------------------------------------------------------------
// demod[b*COUT+oc] = rsqrt(CS2 * sum_ic smod^2 * wsq + eps) * CS
// ---------------------------------------------------------------------------
__global__ __launch_bounds__(256) void demod_kernel(
    const float* __restrict__ smod, const float* __restrict__ wsq,
    float* __restrict__ demod) {
  int wid  = (blockIdx.x << 2) + (threadIdx.x >> 6);
  int lane = threadIdx.x & 63;
  int b  = wid >> 9;
  int oc = wid & 511;
  const float* s = smod + b * CIN;
  const float* w = wsq + (size_t)oc * CIN;
  float sum = 0.f;
#pragma unroll
  for (int k = 0; k < CIN / 64; ++k) {
    float sv = s[lane + 64 * k];
    sum += sv * sv * w[lane + 64 * k];
  }
#pragma unroll
  for (int off = 32; off; off >>= 1) sum += __shfl_down(sum, off, 64);
  if (lane == 0) demod[wid] = rsqrtf(sum * CONV_SCALE2 + 1e-8f) * CONV_SCALE;
}

// ---------------------------------------------------------------------------
// premod: xt[b][g][y][x][ic32] bf16 = input[b][ic][y][x] * smod[b][ic]
// ---------------------------------------------------------------------------
__global__ __launch_bounds__(256) void premod_kernel(
    const float* __restrict__ xin, const float* __restrict__ smod,
    ushort* __restrict__ xt) {
  int n = blockIdx.x * 256 + threadIdx.x;   // < 2,097,152
  int kg = n & 3;
  int x  = (n >> 2) & 63;
  int y  = (n >> 8) & 63;
  int g  = (n >> 14) & 15;
  int b  = n >> 18;
  int ic0 = g * 32 + kg * 8;
  const float* sp = smod + b * CIN + ic0;
  const float* xp = xin + (((size_t)b * CIN + ic0) * HH + y) * WW + x;
  s16x8 o;
#pragma unroll
  for (int j = 0; j < 8; ++j) {
    float v = xp[(size_t)j * HH * WW] * sp[j];
    o[j] = (short)f2bf(v);
  }
  *(s16x8*)(xt + (size_t)n * 8) = o;
}

// ---------------------------------------------------------------------------
// wpack: wfrag[widx=g*9+tap][ocg][lane][8] bf16, exact A-fragment lane order:
//   element = wc[oc = ocg*16 + (l&15)][ic = g*32 + (l>>4)*8 + j][kh][kw]
// ---------------------------------------------------------------------------
__global__ __launch_bounds__(256) void wpack_kernel(
    const float* __restrict__ wc, ushort* __restrict__ wfrag) {
  int n = blockIdx.x * 256 + threadIdx.x;   // < 294,912
  int l = n & 63;
  int rem = n >> 6;
  int ocg = rem & 31;
  int rem2 = rem >> 5;          // < 144
  int tap = rem2 % 9;
  int g   = rem2 / 9;
  int oc  = ocg * 16 + (l & 15);
  int ic0 = g * 32 + (l >> 4) * 8;
  int kh = tap / 3, kw = tap - kh * 3;
  s16x8 o;
#pragma unroll
  for (int j = 0; j < 8; ++j) {
    float v = wc[((size_t)oc * CIN + ic0 + j) * 9 + kh * 3 + kw];
    o[j] = (short)f2bf(v);
  }
  *(s16x8*)(wfrag + (size_t)n * 8) = o;
}

// ---------------------------------------------------------------------------
// conv_mfma: implicit-GEMM 3x3 conv, bf16 MFMA 16x16x32, f32 accum.
// Round-3 schedule: raw s_barrier + lgkmcnt(0)-only drain (vmcnt stays in
// flight across barriers -> weight/xs prefetch latency hides under MFMAs).
// xs double-buffered per g (parity g&1); ws double-buffered per global
// k-step (parity k&1, k = g*9+tap). One barrier per tap, no vmcnt(0) drain.
// ---------------------------------------------------------------------------
#define XS_ROWSZ 4608
#define XS_SIZE  (6 * XS_ROWSZ)    // 27648 B per buffer
#define WS_SIZE  8192

__global__ __launch_bounds__(256, 2) void conv_mfma(
    const ushort* __restrict__ xt,     // [8][16][64][64][32] bf16
    const ushort* __restrict__ wfrag,  // [144][32][64][8] bf16
    const float* __restrict__ demod,
    float* __restrict__ out) {
  __shared__ char lds[2 * XS_SIZE + 2 * WS_SIZE];   // 71,680 B
  char* wsb = lds + 2 * XS_SIZE;

  int tid = threadIdx.x;
  int l = tid & 63, w = tid >> 6;
  int bid = blockIdx.x;
  int ocb = bid & 3;
  int b   = (bid >> 2) & 7;
  int yt  = bid >> 5;           // 0..15
  int y0  = yt * 4;

  f32x4 acc[8][4];
#pragma unroll
  for (int i = 0; i < 8; ++i)
#pragma unroll
    for (int j = 0; j < 4; ++j) acc[i][j] = f32x4{0.f, 0.f, 0.f, 0.f};

  // zero halo columns (ct = 0, 65) in BOTH xs buffers, written once
  if (tid < 96) {
    int r    = tid >> 4;          // 0..5
    int kg   = (tid >> 2) & 3;
    int side = (tid >> 1) & 1;
    int buf  = tid & 1;
    int ct   = side ? 65 : 0;
    int off  = buf * XS_SIZE + r * XS_ROWSZ + (ct >> 3) * 512 + kg * 128 + (ct & 7) * 16;
    *(int4*)(lds + off) = int4{0, 0, 0, 0};
  }

  // staging constants: thread -> (x = tid&63, kg = wave)
  int sx = tid & 63;
  int skg = w;
  int sct = sx + 1;
  int xs_woff = (sct >> 3) * 512 + skg * 128 + (sct & 7) * 16;

  // ---- prologue: stage xs buf0 (g=0) + ws buf0 (widx=0), full drain once ----
  {
    const int4* wsrc = (const int4*)(wfrag + (size_t)(ocb * 8) * 512);
    int4 wv0 = wsrc[tid];
    int4 wv1 = wsrc[tid + 256];
#pragma unroll
    for (int r = 0; r < 6; ++r) {
      int gy = y0 - 1 + r;
      int4 t = {0, 0, 0, 0};
      if (gy >= 0 && gy < HH)
        t = *(const int4*)(xt + ((((size_t)(b * 16 + 0) * 4096) + gy * 64 + sx) * 32 + skg * 8));
      *(int4*)(lds + r * XS_ROWSZ + xs_woff) = t;
    }
    *(int4*)(wsb + tid * 16) = wv0;
    *(int4*)(wsb + tid * 16 + 4096) = wv1;
  }
  __syncthreads();

  int4 xv[6];
  for (int g = 0; g < 16; ++g) {
    char* xs_r = lds + (g & 1) * XS_SIZE;
    char* xs_w = lds + ((g & 1) ^ 1) * XS_SIZE;
#pragma unroll
    for (int tap = 0; tap < 9; ++tap) {
      const int k = g * 9 + tap;
      char* ws_cur = wsb + (k & 1) * WS_SIZE;
      char* ws_nxt = wsb + ((k & 1) ^ 1) * WS_SIZE;

      // issue next-g xs global loads early (hide under 9 taps of MFMA)
      if (tap == 0 && g < 15) {
#pragma unroll
        for (int r = 0; r < 6; ++r) {
          int gy = y0 - 1 + r;
          xv[r] = int4{0, 0, 0, 0};
          if (gy >= 0 && gy < HH)
            xv[r] = *(const int4*)(xt + ((((size_t)(b * 16 + g + 1) * 4096) + gy * 64 + sx) * 32 + skg * 8));
        }
      }
      // issue next k-step's ws global loads (drained only at its ds_write)
      int4 nv0, nv1;
      if (k < 143) {
        const int4* wsrc = (const int4*)(wfrag + ((size_t)(k + 1) * 32 + ocb * 8) * 512);
        nv0 = wsrc[tid];
        nv1 = wsrc[tid + 256];
      }

      const int dy = tap / 3 - 1, dx = tap % 3 - 1;
      const int rb = w + 1 + dy;
      s16x8 bfr[4];
#pragma unroll
      for (int fn = 0; fn < 4; ++fn) {
        int c2 = fn * 16 + (l & 15) + dx + 1;   // 0..65
        bfr[fn] = *(const s16x8*)(xs_r + rb * XS_ROWSZ + (c2 >> 3) * 512 + (l >> 4) * 128 + (c2 & 7) * 16);
      }

      __builtin_amdgcn_s_setprio(1);
#pragma unroll
      for (int fm = 0; fm < 8; ++fm) {
        s16x8 afr = *(const s16x8*)(ws_cur + fm * 1024 + l * 16);
#pragma unroll
        for (int fn = 0; fn < 4; ++fn)
          acc[fm][fn] = __builtin_amdgcn_mfma_f32_16x16x32_bf16(afr, bfr[fn], acc[fm][fn], 0, 0, 0);
      }
      __builtin_amdgcn_s_setprio(0);

      if (k < 143) {
        *(int4*)(ws_nxt + tid * 16) = nv0;
        *(int4*)(ws_nxt + tid * 16 + 4096) = nv1;
      }
      if (tap == 8 && g < 15) {
#pragma unroll
        for (int r = 0; r < 6; ++r)
          *(int4*)(xs_w + r * XS_ROWSZ + xs_woff) = xv[r];
      }

      // barrier with LDS-only drain: vmcnt prefetches stay in flight
      asm volatile("s_waitcnt lgkmcnt(0)" ::: "memory");
      __builtin_amdgcn_sched_barrier(0);
      __builtin_amdgcn_s_barrier();
      __builtin_amdgcn_sched_barrier(0);
    }
  }

  // ---- epilogue: demod scale + store ----
  int oc_base = ocb * 128;
  int gy = y0 + w;
#pragma unroll
  for (int fm = 0; fm < 8; ++fm) {
#pragma unroll
    for (int r = 0; r < 4; ++r) {
      int oc = oc_base + fm * 16 + (l >> 4) * 4 + r;
      float dm = demod[b * COUT + oc];
#pragma unroll
      for (int fn = 0; fn < 4; ++fn) {
        out[(((size_t)b * COUT + oc) * 4096) + gy * 64 + fn * 16 + (l & 15)] =
            acc[fm][fn][r] * dm;
      }
    }
  }
}

// ---------------------------------------------------------------------------
extern "C" void kernel_launch(void* const* d_in, const int* in_sizes, int n_in,
                              void* d_out, int out_size, void* d_ws, size_t ws_size,
                              hipStream_t stream) {
  const float* input = (const float*)d_in[0];  // [8,512,64,64]
  const float* style = (const float*)d_in[1];  // [8,512]
  const float* wa    = (const float*)d_in[2];  // [512,512]
  const float* ba    = (const float*)d_in[3];  // [1,512]
  const float* wconv = (const float*)d_in[4];  // [512,512,3,3]
  float* out = (float*)d_out;

  float* smod  = (float*)d_ws;                    // 4096 f
  float* demod = smod + BB * CIN;                 // 4096 f
  float* wsq   = demod + BB * COUT;               // 262144 f
  ushort* wfrag = (ushort*)(wsq + (size_t)COUT * CIN);   // 2,359,296 us (4.5 MB)
  ushort* xt    = wfrag + (size_t)16 * 9 * 32 * 64 * 8;  // 16,777,216 us (32 MB)

  affine_kernel<<<BB * CIN / 4, 256, 0, stream>>>(style, wa, ba, smod);
  wsq_kernel<<<COUT * CIN / 256, 256, 0, stream>>>(wconv, wsq);
  demod_kernel<<<BB * COUT / 4, 256, 0, stream>>>(smod, wsq, demod);
  wpack_kernel<<<16 * 9 * 32 * 64 / 256, 256, 0, stream>>>(wconv, wfrag);
  premod_kernel<<<BB * 16 * 64 * 64 * 4 / 256, 256, 0, stream>>>(input, smod, xt);
  conv_mfma<<<BB * 4 * 16, 256, 0, stream>>>(xt, wfrag, demod, out);
}